// Round 1
// baseline (567.399 us; speedup 1.0000x reference)
//
#include <hip/hip_runtime.h>

#define HW 9216
#define CDIM 256
#define NBATCH 8
#define NHEADS 8

typedef __bf16 bf16x8 __attribute__((ext_vector_type(8)));
typedef float f32x4 __attribute__((ext_vector_type(4)));
typedef float f32x2 __attribute__((ext_vector_type(2)));
typedef unsigned short us4v __attribute__((ext_vector_type(4)));
typedef unsigned short us2v __attribute__((ext_vector_type(2)));
typedef unsigned int u32x4 __attribute__((ext_vector_type(4)));

__device__ inline unsigned short f2bf(float f) {
    unsigned int u = __builtin_bit_cast(unsigned int, f);
    u = (u + 0x7FFF + ((u >> 16) & 1)) >> 16;
    return (unsigned short)u;
}
__device__ inline float bf2f(unsigned short s) {
    unsigned int u = ((unsigned int)s) << 16;
    return __builtin_bit_cast(float, u);
}
__device__ inline unsigned int pk2(float a, float b) {
    return (unsigned int)f2bf(a) | ((unsigned int)f2bf(b) << 16);
}
__device__ inline void stx(float* p, float v) { *p = v; }
__device__ inline void stx(unsigned short* p, float v) { *p = f2bf(v); }

// ---------------- fuse W_cat @ [W_qr; W_qd] -> bf16 Wq [256][512], fp32 bq ----------------
__global__ void fuse_wq(const float* __restrict__ W_cat, const float* __restrict__ W_qr,
                        const float* __restrict__ W_qd, const float* __restrict__ b_qr,
                        const float* __restrict__ b_qd, const float* __restrict__ b_cat,
                        unsigned short* __restrict__ Wq, float* __restrict__ bq) {
    int o = blockIdx.x;
    int c = threadIdx.x;
    float ax = 0.f, ay = 0.f;
    for (int i = 0; i < 128; ++i) {
        ax += W_cat[o * 256 + i] * W_qr[i * 256 + c];
        ay += W_cat[o * 256 + 128 + i] * W_qd[i * 256 + c];
    }
    Wq[o * 512 + c] = f2bf(ax);
    Wq[o * 512 + 256 + c] = f2bf(ay);
    if (c == 0) {
        float s = b_cat[o];
        for (int i = 0; i < 128; ++i)
            s += W_cat[o * 256 + i] * b_qr[i] + W_cat[o * 256 + 128 + i] * b_qd[i];
        bq[o] = s;
    }
}

// ---------------- convert W_kf, W_vf to bf16 ----------------
__global__ void cvt_w(const float* __restrict__ a, const float* __restrict__ b,
                      unsigned short* __restrict__ oa, unsigned short* __restrict__ ob) {
    int i = blockIdx.x * 256 + threadIdx.x;  // 65536 elements each
    oa[i] = f2bf(a[i]);
    ob[i] = f2bf(b[i]);
}

// ---------------- pipelined MFMA conv1x1 GEMM ----------------
// Out0[b,m,n] = sum_k A0[m,k]*X[b,k,n] + bias0[m] (+resid); DUAL adds Out1 with A1/bias1.
// Block tile: 128(m) x BN(n), BK=64, 4 waves (2x2). Register-prefetch double-buffered LDS.
// LDS layout: cell (q8 = k>>3, n) holds 8 k-contiguous bf16; byte offset XOR-swizzled so
// both staging ds_write_b128 (n-stride NLD lanes) and fragment ds_read_b128 are conflict-free.
template <int BN, bool DUAL, typename TX, typename TOut>
__global__ __launch_bounds__(256, 2) void gemm2(
    const unsigned short* __restrict__ A0, const unsigned short* __restrict__ A1,
    int a_bs, int Ktot,
    const TX* __restrict__ X0, const TX* __restrict__ X1,
    const float* __restrict__ bias0, const float* __restrict__ bias1,
    const float* __restrict__ resid, TOut* __restrict__ O0, TOut* __restrict__ O1) {
    constexpr int NJ = BN / 32;              // 16-col fragments per wave-tile half
    constexpr int NLD = (BN == 128) ? 4 : 2; // floats per staging load
    constexpr int BUFB = 8 * BN * 16;        // bytes per LDS buffer (8 octets x BN x 16B)

    const int b = blockIdx.z;
    const int n0 = blockIdx.x * BN;
    const int m0 = blockIdx.y * 128;
    const int tid = threadIdx.x;
    const int lane = tid & 63;
    const int wid = tid >> 6;
    const int wm = (wid >> 1) * 64;
    const int wn = (wid & 1) * (BN / 2);
    const int l15 = lane & 15;
    const int quad = lane >> 4;

    __shared__ __align__(16) char Bs[2][BUFB];

    const unsigned short* Ab0 = A0 + (size_t)b * a_bs;
    const unsigned short* Ab1 = DUAL ? A1 : nullptr;
    const TX* Xb0 = X0 + (size_t)b * CDIM * HW;
    const TX* Xb1 = X1 ? X1 + (size_t)b * CDIM * HW : nullptr;

    const int sn = (tid & 31) * NLD;   // staged n base
    const int so = (tid >> 5) * 8;     // staged k-octet row base

    f32x4 acc0[4][NJ] = {};
    f32x4 acc1[DUAL ? 4 : 1][NJ] = {};
    float f[8][NLD];

    auto LOADS = [&](int kg) {
        const TX* Xp = (Xb1 && kg >= 256) ? Xb1 : Xb0;
        const int kr = kg & 255;
#pragma unroll
        for (int r = 0; r < 8; ++r) {
            const TX* p = Xp + (size_t)(kr + so + r) * HW + n0 + sn;
            if constexpr (sizeof(TX) == 4) {
                if constexpr (NLD == 4) {
                    f32x4 v = *(const f32x4*)p;
#pragma unroll
                    for (int j = 0; j < 4; ++j) f[r][j] = v[j];
                } else {
                    f32x2 v = *(const f32x2*)p;
                    f[r][0] = v[0]; f[r][1] = v[1];
                }
            } else {
                if constexpr (NLD == 4) {
                    us4v v = *(const us4v*)p;
#pragma unroll
                    for (int j = 0; j < 4; ++j) f[r][j] = bf2f(v[j]);
                } else {
                    us2v v = *(const us2v*)p;
                    f[r][0] = bf2f(v[0]); f[r][1] = bf2f(v[1]);
                }
            }
        }
    };

    auto PKW = [&](int buf) {
        char* base = &Bs[buf][0];
#pragma unroll
        for (int j = 0; j < NLD; ++j) {
            int n = sn + j;
            u32x4 w;
            w[0] = pk2(f[0][j], f[1][j]);
            w[1] = pk2(f[2][j], f[3][j]);
            w[2] = pk2(f[4][j], f[5][j]);
            w[3] = pk2(f[6][j], f[7][j]);
            *(u32x4*)(base + ((((so >> 3) * BN + n) * 16) ^ ((n & 0x38) << 1))) = w;
        }
    };

    auto COMPUTE = [&](int buf, int k0) {
        const char* base = &Bs[buf][0];
#pragma unroll
        for (int kk = 0; kk < 64; kk += 32) {
            bf16x8 bfr[NJ];
#pragma unroll
            for (int nj = 0; nj < NJ; ++nj) {
                int n = wn + nj * 16 + l15;
                bfr[nj] = *(const bf16x8*)(base +
                    (((((kk >> 3) + quad) * BN + n) * 16) ^ ((n & 0x38) << 1)));
            }
            bf16x8 af[4];
#pragma unroll
            for (int mi = 0; mi < 4; ++mi)
                af[mi] = *(const bf16x8*)(Ab0 + (size_t)(m0 + wm + mi * 16 + l15) * Ktot +
                                          k0 + kk + quad * 8);
#pragma unroll
            for (int mi = 0; mi < 4; ++mi)
#pragma unroll
                for (int nj = 0; nj < NJ; ++nj)
                    acc0[mi][nj] = __builtin_amdgcn_mfma_f32_16x16x32_bf16(af[mi], bfr[nj],
                                                                           acc0[mi][nj], 0, 0, 0);
            if constexpr (DUAL) {
#pragma unroll
                for (int mi = 0; mi < 4; ++mi)
                    af[mi] = *(const bf16x8*)(Ab1 + (size_t)(m0 + wm + mi * 16 + l15) * Ktot +
                                              k0 + kk + quad * 8);
#pragma unroll
                for (int mi = 0; mi < 4; ++mi)
#pragma unroll
                    for (int nj = 0; nj < NJ; ++nj)
                        acc1[mi][nj] = __builtin_amdgcn_mfma_f32_16x16x32_bf16(af[mi], bfr[nj],
                                                                               acc1[mi][nj], 0, 0, 0);
            }
        }
    };

    const int nt = Ktot >> 6;
    // prologue: stage k-chunk 0
    LOADS(0);
    PKW(0);
    // main loop: issue loads for t+1 BEFORE the barrier (prefetch pinned early by s_barrier),
    // consume them (vmcnt wait) only at PKW after the MFMAs -> HBM latency hidden.
    for (int t = 0; t < nt - 1; ++t) {
        LOADS((t + 1) << 6);
        __syncthreads();
        COMPUTE(t & 1, t << 6);
        PKW((t + 1) & 1);
    }
    __syncthreads();
    COMPUTE((nt - 1) & 1, (nt - 1) << 6);

    // ---- epilogue: C/D layout col(n)=lane&15, row(m)=quad*4+reg ----
#pragma unroll
    for (int mi = 0; mi < 4; ++mi) {
#pragma unroll
        for (int r = 0; r < 4; ++r) {
            int m = m0 + wm + mi * 16 + quad * 4 + r;
            float bv = bias0[m];
#pragma unroll
            for (int nj = 0; nj < NJ; ++nj) {
                int n = n0 + wn + nj * 16 + l15;
                size_t off = ((size_t)b * CDIM + m) * HW + n;
                float v = acc0[mi][nj][r] + bv;
                if (resid) v += resid[off];
                stx(&O0[off], v);
            }
        }
    }
    if constexpr (DUAL) {
#pragma unroll
        for (int mi = 0; mi < 4; ++mi) {
#pragma unroll
            for (int r = 0; r < 4; ++r) {
                int m = m0 + wm + mi * 16 + quad * 4 + r;
                float bv = bias1[m];
#pragma unroll
                for (int nj = 0; nj < NJ; ++nj) {
                    int n = n0 + wn + nj * 16 + l15;
                    size_t off = ((size_t)b * CDIM + m) * HW + n;
                    stx(&O1[off], acc1[mi][nj][r] + bv);
                }
            }
        }
    }
}

// ---------------- Gram + sum-of-squares (per b,h; chunked over n, atomic accumulate) ----
__global__ __launch_bounds__(256) void gram_kernel(
    const unsigned short* __restrict__ q, const unsigned short* __restrict__ k,
    float* __restrict__ G, float* __restrict__ sqq, float* __restrict__ sqk) {
    const int nc = blockIdx.x;   // 72 chunks of 128
    const int h = blockIdx.y, b = blockIdx.z;
    const int t = threadIdx.x;

    __shared__ float qs[32][128];
    __shared__ float ks[32][129];

    size_t base = ((size_t)b * CDIM + h * 32) * HW + nc * 128;
#pragma unroll
    for (int i = 0; i < 4; ++i) {
        int idx = i * 256 + t;          // 1024 groups of 4
        int row = idx >> 5, c4 = (idx & 31) * 4;
        us4v qv = *(const us4v*)(q + base + (size_t)row * HW + c4);
        us4v kv = *(const us4v*)(k + base + (size_t)row * HW + c4);
#pragma unroll
        for (int j = 0; j < 4; ++j) {
            qs[row][c4 + j] = bf2f(qv[j]);
            ks[row][c4 + j] = bf2f(kv[j]);
        }
    }
    __syncthreads();

    const int d = t & 31;
    const int cb = t >> 5;
    float acc[4] = {0.f, 0.f, 0.f, 0.f};
    for (int n = 0; n < 128; ++n) {
        float kv = ks[d][n];
#pragma unroll
        for (int p = 0; p < 4; ++p) acc[p] += qs[cb + 8 * p][n] * kv;
    }

    float* Gp = G + (size_t)(b * 8 + h) * 32 * 32;
#pragma unroll
    for (int p = 0; p < 4; ++p) atomicAdd(&Gp[(cb + 8 * p) * 32 + d], acc[p]);

    if (t < 64) {
        int c = t & 31;
        float sq = 0.f;
        if (t < 32) {
            for (int n = 0; n < 128; ++n) { float v = qs[c][n]; sq += v * v; }
            atomicAdd(&sqq[(b * 8 + h) * 32 + c], sq);
        } else {
            for (int n = 0; n < 128; ++n) { float v = ks[c][n]; sq += v * v; }
            atomicAdd(&sqk[(b * 8 + h) * 32 + c], sq);
        }
    }
}

// ---------------- normalize + temperature + softmax ----------------
__global__ __launch_bounds__(1024) void softmax_kernel(
    const float* __restrict__ G, const float* __restrict__ sqq,
    const float* __restrict__ sqk, const float* __restrict__ temp,
    float* __restrict__ A) {
    int bh = blockIdx.x;
    int h = bh & 7;
    int c = threadIdx.y, d = threadIdx.x;
    float nq = fmaxf(sqrtf(sqq[bh * 32 + c]), 1e-12f);
    float nk = fmaxf(sqrtf(sqk[bh * 32 + d]), 1e-12f);
    float v = G[(size_t)(bh * 32 + c) * 32 + d] / (nq * nk) * temp[h];
    float m = v;
    for (int s = 16; s > 0; s >>= 1) m = fmaxf(m, __shfl_xor(m, s, 32));
    float e = __expf(v - m);
    float sum = e;
    for (int s = 16; s > 0; s >>= 1) sum += __shfl_xor(sum, s, 32);
    A[(size_t)(bh * 32 + c) * 32 + d] = e / sum;
}

// ---------------- M_b[o, h*32+d] = sum_c W_proj[o, h*32+c] * A[b,h,c,d] -> bf16 ----------------
__global__ __launch_bounds__(256) void build_m(const float* __restrict__ W_proj,
                                               const float* __restrict__ A,
                                               unsigned short* __restrict__ M) {
    int o = blockIdx.x;
    int b = blockIdx.y;
    int t = threadIdx.x;
    int h = t >> 5, d = t & 31;
    const float* Ab = A + (size_t)(b * 8 + h) * 32 * 32;
    float acc = 0.f;
    for (int c = 0; c < 32; ++c)
        acc += W_proj[o * 256 + h * 32 + c] * Ab[c * 32 + d];
    M[((size_t)b * 256 + o) * 256 + t] = f2bf(acc);
}

extern "C" void kernel_launch(void* const* d_in, const int* in_sizes, int n_in,
                              void* d_out, int out_size, void* d_ws, size_t ws_size,
                              hipStream_t stream) {
    const float* x = (const float*)d_in[0];
    const float* y = (const float*)d_in[1];
    const float* z = (const float*)d_in[2];
    const float* W_qr = (const float*)d_in[3];
    const float* b_qr = (const float*)d_in[4];
    const float* W_qd = (const float*)d_in[5];
    const float* b_qd = (const float*)d_in[6];
    const float* W_kf = (const float*)d_in[7];
    const float* b_kf = (const float*)d_in[8];
    const float* W_vf = (const float*)d_in[9];
    const float* b_vf = (const float*)d_in[10];
    const float* W_cat = (const float*)d_in[11];
    const float* b_cat = (const float*)d_in[12];
    const float* W_proj = (const float*)d_in[13];
    const float* b_proj = (const float*)d_in[14];
    const float* temp = (const float*)d_in[15];
    float* out = (float*)d_out;

    char* ws = (char*)d_ws;
    const size_t NT = (size_t)NBATCH * CDIM * HW;  // elements per tensor
    unsigned short* qb = (unsigned short*)ws;
    unsigned short* kb = qb + NT;
    unsigned short* vb = kb + NT;
    char* p = (char*)(vb + NT);
    unsigned short* Wq = (unsigned short*)p;  p += 256 * 512 * 2;
    unsigned short* Wk = (unsigned short*)p;  p += 256 * 256 * 2;
    unsigned short* Wv = (unsigned short*)p;  p += 256 * 256 * 2;
    float* bq  = (float*)p;                   p += 1024;
    float* G   = (float*)p;                   p += 64 * 32 * 32 * 4;
    float* sqq = (float*)p;                   p += 2048 * 4;
    float* sqk = (float*)p;                   p += 2048 * 4;
    float* Aat = (float*)p;                   p += 64 * 32 * 32 * 4;
    unsigned short* Mb = (unsigned short*)p;  p += (size_t)8 * 256 * 256 * 2;

    hipMemsetAsync(G, 0, 262144 + 8192 + 8192, stream);

    fuse_wq<<<256, 256, 0, stream>>>(W_cat, W_qr, W_qd, b_qr, b_qd, b_cat, Wq, bq);
    cvt_w<<<256, 256, 0, stream>>>(W_kf, W_vf, Wk, Wv);

    // q = Wq @ [x;y]  (K=512, bf16 out)
    gemm2<128, false, float, unsigned short><<<dim3(HW / 128, 2, NBATCH), 256, 0, stream>>>(
        Wq, nullptr, 0, 512, x, y, bq, nullptr, nullptr, qb, nullptr);
    // fused k,v = Wk@z, Wv@z  (z staged once)
    gemm2<64, true, float, unsigned short><<<dim3(HW / 64, 2, NBATCH), 256, 0, stream>>>(
        Wk, Wv, 0, 256, z, nullptr, b_kf, b_vf, nullptr, kb, vb);

    gram_kernel<<<dim3(HW / 128, NHEADS, NBATCH), 256, 0, stream>>>(qb, kb, G, sqq, sqk);
    softmax_kernel<<<64, dim3(32, 32), 0, stream>>>(G, sqq, sqk, temp, Aat);
    build_m<<<dim3(256, 8), 256, 0, stream>>>(W_proj, Aat, Mb);

    // out = (W_proj@A) @ v + b_proj + z
    gemm2<128, false, unsigned short, float><<<dim3(HW / 128, 2, NBATCH), 256, 0, stream>>>(
        Mb, nullptr, 256 * 256, 256, vb, nullptr, b_proj, nullptr, z, out, nullptr);
}

// Round 2
// 517.630 us; speedup vs baseline: 1.0961x; 1.0961x over previous
//
#include <hip/hip_runtime.h>

#define HW 9216
#define CDIM 256
#define NBATCH 8
#define NHEADS 8
#define GCH 9      // gram n-chunks (9 * 1024 = 9216)

typedef __bf16 bf16x8 __attribute__((ext_vector_type(8)));
typedef float f32x4 __attribute__((ext_vector_type(4)));
typedef float f32x2 __attribute__((ext_vector_type(2)));
typedef float f32x16 __attribute__((ext_vector_type(16)));
typedef unsigned short us2v __attribute__((ext_vector_type(2)));
typedef unsigned short us4v __attribute__((ext_vector_type(4)));
typedef unsigned short us8v __attribute__((ext_vector_type(8)));
typedef unsigned int u32x4 __attribute__((ext_vector_type(4)));

__device__ inline unsigned short f2bf(float f) {
    unsigned int u = __builtin_bit_cast(unsigned int, f);
    u = (u + 0x7FFF + ((u >> 16) & 1)) >> 16;
    return (unsigned short)u;
}
__device__ inline float bf2f(unsigned short s) {
    unsigned int u = ((unsigned int)s) << 16;
    return __builtin_bit_cast(float, u);
}
__device__ inline unsigned int pk2(float a, float b) {
    return (unsigned int)f2bf(a) | ((unsigned int)f2bf(b) << 16);
}
__device__ inline void stx(float* p, float v) { *p = v; }
__device__ inline void stx(unsigned short* p, float v) { *p = f2bf(v); }

// ---------------- fuse W_cat @ [W_qr; W_qd] -> bf16 Wq [256][512], fp32 bq ----------------
__global__ void fuse_wq(const float* __restrict__ W_cat, const float* __restrict__ W_qr,
                        const float* __restrict__ W_qd, const float* __restrict__ b_qr,
                        const float* __restrict__ b_qd, const float* __restrict__ b_cat,
                        unsigned short* __restrict__ Wq, float* __restrict__ bq) {
    int o = blockIdx.x;
    int c = threadIdx.x;
    float ax = 0.f, ay = 0.f;
    for (int i = 0; i < 128; ++i) {
        ax += W_cat[o * 256 + i] * W_qr[i * 256 + c];
        ay += W_cat[o * 256 + 128 + i] * W_qd[i * 256 + c];
    }
    Wq[o * 512 + c] = f2bf(ax);
    Wq[o * 512 + 256 + c] = f2bf(ay);
    if (c == 0) {
        float s = b_cat[o];
        for (int i = 0; i < 128; ++i)
            s += W_cat[o * 256 + i] * b_qr[i] + W_cat[o * 256 + 128 + i] * b_qd[i];
        bq[o] = s;
    }
}

// ---------------- convert W_kf, W_vf to bf16 ----------------
__global__ void cvt_w(const float* __restrict__ a, const float* __restrict__ b,
                      unsigned short* __restrict__ oa, unsigned short* __restrict__ ob) {
    int i = blockIdx.x * 256 + threadIdx.x;  // 65536 elements each
    oa[i] = f2bf(a[i]);
    ob[i] = f2bf(b[i]);
}

// ---------------- pipelined MFMA conv1x1 GEMM ----------------
// Out0[b,m,n] = sum_k A0[m,k]*X[b,k,n] + bias0[m] (+resid); DUAL adds Out1 with A1/bias1.
// Block tile: 128(m) x BN(n), BK=64, 4 waves (2x2). Register-staged, double-buffered LDS.
// Pipeline order per step (T14 async-STAGE split): issue global loads for t+1, THEN compute
// tile t (loads in flight under MFMAs), THEN pack+ds_write t+1 (vmcnt consumed here), THEN
// __syncthreads (its vmcnt(0) drain is already satisfied -> barrier costs only lgkm).
template <int BN, bool DUAL, typename TX, typename TOut>
__global__ __launch_bounds__(256, 2) void gemm2(
    const unsigned short* __restrict__ A0, const unsigned short* __restrict__ A1,
    int a_bs, int Ktot,
    const TX* __restrict__ X0, const TX* __restrict__ X1,
    const float* __restrict__ bias0, const float* __restrict__ bias1,
    const float* __restrict__ resid, TOut* __restrict__ O0, TOut* __restrict__ O1) {
    constexpr int NJ = BN / 32;              // 16-col fragments per wave-tile half
    constexpr int NLD = (BN == 128) ? 4 : 2; // floats per staging load
    constexpr int BUFB = 8 * BN * 16;        // bytes per LDS buffer (8 octets x BN x 16B)

    const int b = blockIdx.z;
    const int n0 = blockIdx.x * BN;
    const int m0 = blockIdx.y * 128;
    const int tid = threadIdx.x;
    const int lane = tid & 63;
    const int wid = tid >> 6;
    const int wm = (wid >> 1) * 64;
    const int wn = (wid & 1) * (BN / 2);
    const int l15 = lane & 15;
    const int quad = lane >> 4;

    __shared__ __align__(16) char Bs[2][BUFB];

    const unsigned short* Ab0 = A0 + (size_t)b * a_bs;
    const unsigned short* Ab1 = DUAL ? A1 : nullptr;
    const TX* Xb0 = X0 + (size_t)b * CDIM * HW;
    const TX* Xb1 = X1 ? X1 + (size_t)b * CDIM * HW : nullptr;

    const int sn = (tid & 31) * NLD;   // staged n base
    const int so = (tid >> 5) * 8;     // staged k-octet row base

    f32x4 acc0[4][NJ] = {};
    f32x4 acc1[DUAL ? 4 : 1][NJ] = {};
    float f[8][NLD];

    auto LOADS = [&](int kg) {
        const TX* Xp = (Xb1 && kg >= 256) ? Xb1 : Xb0;
        const int kr = kg & 255;
#pragma unroll
        for (int r = 0; r < 8; ++r) {
            const TX* p = Xp + (size_t)(kr + so + r) * HW + n0 + sn;
            if constexpr (sizeof(TX) == 4) {
                if constexpr (NLD == 4) {
                    f32x4 v = *(const f32x4*)p;
#pragma unroll
                    for (int j = 0; j < 4; ++j) f[r][j] = v[j];
                } else {
                    f32x2 v = *(const f32x2*)p;
                    f[r][0] = v[0]; f[r][1] = v[1];
                }
            } else {
                if constexpr (NLD == 4) {
                    us4v v = *(const us4v*)p;
#pragma unroll
                    for (int j = 0; j < 4; ++j) f[r][j] = bf2f(v[j]);
                } else {
                    us2v v = *(const us2v*)p;
                    f[r][0] = bf2f(v[0]); f[r][1] = bf2f(v[1]);
                }
            }
        }
    };

    auto PKW = [&](int buf) {
        char* base = &Bs[buf][0];
#pragma unroll
        for (int j = 0; j < NLD; ++j) {
            int n = sn + j;
            u32x4 w;
            w[0] = pk2(f[0][j], f[1][j]);
            w[1] = pk2(f[2][j], f[3][j]);
            w[2] = pk2(f[4][j], f[5][j]);
            w[3] = pk2(f[6][j], f[7][j]);
            *(u32x4*)(base + ((((so >> 3) * BN + n) * 16) ^ ((n & 0x38) << 1))) = w;
        }
    };

    auto COMPUTE = [&](int buf, int k0) {
        const char* base = &Bs[buf][0];
#pragma unroll
        for (int kk = 0; kk < 64; kk += 32) {
            bf16x8 bfr[NJ];
#pragma unroll
            for (int nj = 0; nj < NJ; ++nj) {
                int n = wn + nj * 16 + l15;
                bfr[nj] = *(const bf16x8*)(base +
                    (((((kk >> 3) + quad) * BN + n) * 16) ^ ((n & 0x38) << 1)));
            }
            bf16x8 af[4];
#pragma unroll
            for (int mi = 0; mi < 4; ++mi)
                af[mi] = *(const bf16x8*)(Ab0 + (size_t)(m0 + wm + mi * 16 + l15) * Ktot +
                                          k0 + kk + quad * 8);
#pragma unroll
            for (int mi = 0; mi < 4; ++mi)
#pragma unroll
                for (int nj = 0; nj < NJ; ++nj)
                    acc0[mi][nj] = __builtin_amdgcn_mfma_f32_16x16x32_bf16(af[mi], bfr[nj],
                                                                           acc0[mi][nj], 0, 0, 0);
            if constexpr (DUAL) {
#pragma unroll
                for (int mi = 0; mi < 4; ++mi)
                    af[mi] = *(const bf16x8*)(Ab1 + (size_t)(m0 + wm + mi * 16 + l15) * Ktot +
                                              k0 + kk + quad * 8);
#pragma unroll
                for (int mi = 0; mi < 4; ++mi)
#pragma unroll
                    for (int nj = 0; nj < NJ; ++nj)
                        acc1[mi][nj] = __builtin_amdgcn_mfma_f32_16x16x32_bf16(af[mi], bfr[nj],
                                                                               acc1[mi][nj], 0, 0, 0);
            }
        }
    };

    const int nt = Ktot >> 6;
    LOADS(0);
    PKW(0);
    __syncthreads();
    for (int t = 0; t < nt - 1; ++t) {
        LOADS((t + 1) << 6);                 // issue next tile's loads (stay in flight)
        __builtin_amdgcn_sched_barrier(0);   // pin: don't sink loads below the MFMAs
        COMPUTE(t & 1, t << 6);              // compute current tile under load latency
        PKW((t + 1) & 1);                    // vmcnt consumed here, after compute
        __syncthreads();                     // vmcnt already 0 -> drain is free
    }
    COMPUTE((nt - 1) & 1, (nt - 1) << 6);

    // ---- epilogue: C/D layout col(n)=lane&15, row(m)=quad*4+reg ----
#pragma unroll
    for (int mi = 0; mi < 4; ++mi) {
#pragma unroll
        for (int r = 0; r < 4; ++r) {
            int m = m0 + wm + mi * 16 + quad * 4 + r;
            float bv = bias0[m];
#pragma unroll
            for (int nj = 0; nj < NJ; ++nj) {
                int n = n0 + wn + nj * 16 + l15;
                size_t off = ((size_t)b * CDIM + m) * HW + n;
                float v = acc0[mi][nj][r] + bv;
                if (resid) v += resid[off];
                stx(&O0[off], v);
            }
        }
    }
    if constexpr (DUAL) {
#pragma unroll
        for (int mi = 0; mi < 4; ++mi) {
#pragma unroll
            for (int r = 0; r < 4; ++r) {
                int m = m0 + wm + mi * 16 + quad * 4 + r;
                float bv = bias1[m];
#pragma unroll
                for (int nj = 0; nj < NJ; ++nj) {
                    int n = n0 + wn + nj * 16 + l15;
                    size_t off = ((size_t)b * CDIM + m) * HW + n;
                    stx(&O1[off], acc1[mi][nj][r] + bv);
                }
            }
        }
    }
}

// ---------------- MFMA Gram: G[bh][c][d] = sum_n q[c,n]k[d,n], + row sum-of-squares ------
// Grid (GCH, 64): each block covers 1024 n for one (b,h); 4 waves x 256 n each.
// A-frag = q rows (lane&31), B-frag = k rows (lane&31), k-dim = n (contiguous bf16x8).
// No LDS staging, no atomics: per-chunk partials, summed in softmax_kernel.
__global__ __launch_bounds__(256) void gram_mfma(
    const unsigned short* __restrict__ q, const unsigned short* __restrict__ k,
    float* __restrict__ Gp, float* __restrict__ sqp, float* __restrict__ skp) {
    const int ch = blockIdx.x;
    const int bh = blockIdx.y;
    const int t = threadIdx.x;
    const int lane = t & 63, w = t >> 6;
    const int row = lane & 31, half = lane >> 5;

    const size_t rb = ((size_t)bh * 32 + row) * HW + ch * 1024 + w * 256 + half * 8;
    const unsigned short* qp = q + rb;
    const unsigned short* kp = k + rb;

    f32x16 acc = {};
    float sq = 0.f, sk = 0.f;
#pragma unroll
    for (int n = 0; n < 256; n += 16) {
        us8v rq = *(const us8v*)(qp + n);
        us8v rk = *(const us8v*)(kp + n);
        bf16x8 aq = __builtin_bit_cast(bf16x8, rq);
        bf16x8 ak = __builtin_bit_cast(bf16x8, rk);
        acc = __builtin_amdgcn_mfma_f32_32x32x16_bf16(aq, ak, acc, 0, 0, 0);
#pragma unroll
        for (int j = 0; j < 8; ++j) {
            float fq = bf2f(rq[j]);
            float fk = bf2f(rk[j]);
            sq += fq * fq;
            sk += fk * fk;
        }
    }
    // combine the two n-halves of each row (lanes l and l^32 hold the same row)
    sq += __shfl_xor(sq, 32, 64);
    sk += __shfl_xor(sk, 32, 64);

    __shared__ float gs[4][1024];
    __shared__ float sqs[4][32];
    __shared__ float sks[4][32];
    if (half == 0) { sqs[w][row] = sq; sks[w][row] = sk; }
    // C/D layout (32x32): col = lane&31, row = (reg&3) + 8*(reg>>2) + 4*(lane>>5)
#pragma unroll
    for (int r = 0; r < 16; ++r) {
        int cr = (r & 3) + 8 * (r >> 2) + 4 * half;
        gs[w][cr * 32 + row] = acc[r];
    }
    __syncthreads();

    float* Gpo = Gp + ((size_t)ch * 64 + bh) * 1024;
#pragma unroll
    for (int j = 0; j < 4; ++j) {
        int idx = j * 256 + t;
        Gpo[idx] = gs[0][idx] + gs[1][idx] + gs[2][idx] + gs[3][idx];
    }
    if (t < 32)
        sqp[((size_t)ch * 64 + bh) * 32 + t] = sqs[0][t] + sqs[1][t] + sqs[2][t] + sqs[3][t];
    else if (t < 64) {
        int c = t - 32;
        skp[((size_t)ch * 64 + bh) * 32 + c] = sks[0][c] + sks[1][c] + sks[2][c] + sks[3][c];
    }
}

// ---------------- sum partials + normalize + temperature + softmax ----------------
__global__ __launch_bounds__(1024) void softmax_kernel(
    const float* __restrict__ Gp, const float* __restrict__ sqp,
    const float* __restrict__ skp, const float* __restrict__ temp,
    float* __restrict__ A) {
    int bh = blockIdx.x;
    int h = bh & 7;
    int c = threadIdx.y, d = threadIdx.x;
    float g = 0.f, qq = 0.f, kk = 0.f;
#pragma unroll
    for (int ch = 0; ch < GCH; ++ch) {
        g += Gp[((size_t)ch * 64 + bh) * 1024 + c * 32 + d];
        qq += sqp[((size_t)ch * 64 + bh) * 32 + c];
        kk += skp[((size_t)ch * 64 + bh) * 32 + d];
    }
    float nq = fmaxf(sqrtf(qq), 1e-12f);
    float nk = fmaxf(sqrtf(kk), 1e-12f);
    float v = g / (nq * nk) * temp[h];
    float m = v;
    for (int s = 16; s > 0; s >>= 1) m = fmaxf(m, __shfl_xor(m, s, 32));
    float e = __expf(v - m);
    float sum = e;
    for (int s = 16; s > 0; s >>= 1) sum += __shfl_xor(sum, s, 32);
    A[(size_t)(bh * 32 + c) * 32 + d] = e / sum;
}

// ---------------- M_b[o, h*32+d] = sum_c W_proj[o, h*32+c] * A[b,h,c,d] -> bf16 ----------------
__global__ __launch_bounds__(256) void build_m(const float* __restrict__ W_proj,
                                               const float* __restrict__ A,
                                               unsigned short* __restrict__ M) {
    int o = blockIdx.x;
    int b = blockIdx.y;
    int t = threadIdx.x;
    int h = t >> 5, d = t & 31;
    const float* Ab = A + (size_t)(b * 8 + h) * 32 * 32;
    float acc = 0.f;
    for (int c = 0; c < 32; ++c)
        acc += W_proj[o * 256 + h * 32 + c] * Ab[c * 32 + d];
    M[((size_t)b * 256 + o) * 256 + t] = f2bf(acc);
}

extern "C" void kernel_launch(void* const* d_in, const int* in_sizes, int n_in,
                              void* d_out, int out_size, void* d_ws, size_t ws_size,
                              hipStream_t stream) {
    const float* x = (const float*)d_in[0];
    const float* y = (const float*)d_in[1];
    const float* z = (const float*)d_in[2];
    const float* W_qr = (const float*)d_in[3];
    const float* b_qr = (const float*)d_in[4];
    const float* W_qd = (const float*)d_in[5];
    const float* b_qd = (const float*)d_in[6];
    const float* W_kf = (const float*)d_in[7];
    const float* b_kf = (const float*)d_in[8];
    const float* W_vf = (const float*)d_in[9];
    const float* b_vf = (const float*)d_in[10];
    const float* W_cat = (const float*)d_in[11];
    const float* b_cat = (const float*)d_in[12];
    const float* W_proj = (const float*)d_in[13];
    const float* b_proj = (const float*)d_in[14];
    const float* temp = (const float*)d_in[15];
    float* out = (float*)d_out;

    char* ws = (char*)d_ws;
    const size_t NT = (size_t)NBATCH * CDIM * HW;  // elements per tensor
    unsigned short* qb = (unsigned short*)ws;
    unsigned short* kb = qb + NT;
    unsigned short* vb = kb + NT;
    char* p = (char*)(vb + NT);
    unsigned short* Wq = (unsigned short*)p;  p += 256 * 512 * 2;
    unsigned short* Wk = (unsigned short*)p;  p += 256 * 256 * 2;
    unsigned short* Wv = (unsigned short*)p;  p += 256 * 256 * 2;
    float* bq  = (float*)p;                   p += 1024;
    float* Gp  = (float*)p;                   p += (size_t)GCH * 64 * 1024 * 4;
    float* sqp = (float*)p;                   p += GCH * 64 * 32 * 4;
    float* skp = (float*)p;                   p += GCH * 64 * 32 * 4;
    float* Aat = (float*)p;                   p += 64 * 32 * 32 * 4;
    unsigned short* Mb = (unsigned short*)p;  p += (size_t)8 * 256 * 256 * 2;

    fuse_wq<<<256, 256, 0, stream>>>(W_cat, W_qr, W_qd, b_qr, b_qd, b_cat, Wq, bq);
    cvt_w<<<256, 256, 0, stream>>>(W_kf, W_vf, Wk, Wv);

    // q = Wq @ [x;y]  (K=512, bf16 out)
    gemm2<128, false, float, unsigned short><<<dim3(HW / 128, 2, NBATCH), 256, 0, stream>>>(
        Wq, nullptr, 0, 512, x, y, bq, nullptr, nullptr, qb, nullptr);
    // fused k,v = Wk@z, Wv@z  (z staged once)
    gemm2<64, true, float, unsigned short><<<dim3(HW / 64, 2, NBATCH), 256, 0, stream>>>(
        Wk, Wv, 0, 256, z, nullptr, b_kf, b_vf, nullptr, kb, vb);

    gram_mfma<<<dim3(GCH, 64), 256, 0, stream>>>(qb, kb, Gp, sqp, skp);
    softmax_kernel<<<64, dim3(32, 32), 0, stream>>>(Gp, sqp, skp, temp, Aat);
    build_m<<<dim3(256, 8), 256, 0, stream>>>(W_proj, Aat, Mb);

    // out = (W_proj@A) @ v + b_proj + z
    gemm2<128, false, unsigned short, float><<<dim3(HW / 128, 2, NBATCH), 256, 0, stream>>>(
        Mb, nullptr, 256 * 256, 256, vb, nullptr, b_proj, nullptr, z, out, nullptr);
}

// Round 3
// 492.514 us; speedup vs baseline: 1.1520x; 1.0510x over previous
//
#include <hip/hip_runtime.h>

#define HW 9216
#define CDIM 256
#define NBATCH 8
#define NHEADS 8
#define GCH 9      // gram n-chunks (9 * 1024 = 9216)

typedef __bf16 bf16x8 __attribute__((ext_vector_type(8)));
typedef float f32x4 __attribute__((ext_vector_type(4)));
typedef float f32x2 __attribute__((ext_vector_type(2)));
typedef float f32x16 __attribute__((ext_vector_type(16)));
typedef unsigned short us2v __attribute__((ext_vector_type(2)));
typedef unsigned short us4v __attribute__((ext_vector_type(4)));
typedef unsigned short us8v __attribute__((ext_vector_type(8)));
typedef unsigned int u32x4 __attribute__((ext_vector_type(4)));

__device__ inline unsigned short f2bf(float f) {
    unsigned int u = __builtin_bit_cast(unsigned int, f);
    u = (u + 0x7FFF + ((u >> 16) & 1)) >> 16;
    return (unsigned short)u;
}
__device__ inline float bf2f(unsigned short s) {
    unsigned int u = ((unsigned int)s) << 16;
    return __builtin_bit_cast(float, u);
}
__device__ inline unsigned int pk2(float a, float b) {
    return (unsigned int)f2bf(a) | ((unsigned int)f2bf(b) << 16);
}
__device__ inline void stx(float* p, float v) { *p = v; }
__device__ inline void stx(unsigned short* p, float v) { *p = f2bf(v); }

// ---------------- fuse W_cat @ [W_qr; W_qd] -> bf16 Wq [256][512], fp32 bq ----------------
__global__ void fuse_wq(const float* __restrict__ W_cat, const float* __restrict__ W_qr,
                        const float* __restrict__ W_qd, const float* __restrict__ b_qr,
                        const float* __restrict__ b_qd, const float* __restrict__ b_cat,
                        unsigned short* __restrict__ Wq, float* __restrict__ bq) {
    int o = blockIdx.x;
    int c = threadIdx.x;
    float ax = 0.f, ay = 0.f;
    for (int i = 0; i < 128; ++i) {
        ax += W_cat[o * 256 + i] * W_qr[i * 256 + c];
        ay += W_cat[o * 256 + 128 + i] * W_qd[i * 256 + c];
    }
    Wq[o * 512 + c] = f2bf(ax);
    Wq[o * 512 + 256 + c] = f2bf(ay);
    if (c == 0) {
        float s = b_cat[o];
        for (int i = 0; i < 128; ++i)
            s += W_cat[o * 256 + i] * b_qr[i] + W_cat[o * 256 + 128 + i] * b_qd[i];
        bq[o] = s;
    }
}

// ---------------- convert W_kf, W_vf to bf16 ----------------
__global__ void cvt_w(const float* __restrict__ a, const float* __restrict__ b,
                      unsigned short* __restrict__ oa, unsigned short* __restrict__ ob) {
    int i = blockIdx.x * 256 + threadIdx.x;  // 65536 elements each
    oa[i] = f2bf(a[i]);
    ob[i] = f2bf(b[i]);
}

// ---------------- wide-fetch pipelined MFMA conv1x1 GEMM ----------------
// Out0[b,m,n] = sum_k A0[m,k]*X[b,k,n] + bias0[m] (+resid); DUAL adds Out1 with A1/bias1.
// BM=64, BN=256, BK=32, 512 threads (8 waves of 64x32). Both A and B staged per-step in
// double-buffered LDS; ALL global loads issue at one point, COMPUTE is pure LDS+MFMA, so
// the single vmcnt wait lands after the MFMAs (no vmcnt(0) drain before compute).
// A wave's B-load instruction covers 1KB contiguous per k-row (DRAM page friendly).
template <bool DUAL, typename TX, typename TOut>
__global__ __launch_bounds__(512, 4) void gemm3(
    const unsigned short* __restrict__ A0, const unsigned short* __restrict__ A1,
    int a_bs, int Ktot,
    const TX* __restrict__ X0, const TX* __restrict__ X1,
    const float* __restrict__ bias0, const float* __restrict__ bias1,
    const float* __restrict__ resid, TOut* __restrict__ O0, TOut* __restrict__ O1) {
    constexpr int ROWSA = DUAL ? 128 : 64;   // A rows staged per step (both mats if DUAL)
    constexpr int ABYTES = 4 * ROWSA * 16;   // 4 k-octets x rows x 16B
    constexpr int BBYTES = 4 * 256 * 16;     // 4 k-octets x 256 n x 16B

    __shared__ __align__(16) char As[2][ABYTES];
    __shared__ __align__(16) char Bs[2][BBYTES];

    // XCD-chunked swizzle (1152 blocks, 144/XCD): m-sibling blocks (same B-panel) adjacent
    // -> same XCD L2 serves the shared B-panel once. Bijective since 1152 % 8 == 0.
    const int h = blockIdx.x;
    const int lid = (h & 7) * 144 + (h >> 3);
    const int by = lid & 3;                 // m-block
    const int bx = (lid >> 2) % 36;         // n-panel
    const int bz = (lid >> 2) / 36;         // batch
    const int m0 = by * 64;
    const int n0 = bx * 256;

    const int tid = threadIdx.x;
    const int lane = tid & 63;
    const int wid = tid >> 6;
    const int l15 = lane & 15;
    const int quad = lane >> 4;
    const int wn = wid * 32;

    const unsigned short* Ab0 = A0 + (size_t)bz * a_bs;
    const unsigned short* Ab1 = DUAL ? A1 : nullptr;
    const TX* Xb0 = X0 + (size_t)bz * CDIM * HW;
    const TX* Xb1 = X1 ? X1 + (size_t)bz * CDIM * HW : nullptr;

    // B staging ownership: thread covers 8 k-rows (one octet) x 2 cols
    const int bc = (tid & 127) * 2;
    const int brg = tid >> 7;               // k-octet
    // A staging ownership: linear slot = tid
    const int aq8 = DUAL ? (tid >> 7) : (tid >> 6);
    const int arow = DUAL ? (tid & 127) : (tid & 63);
    const int amat = DUAL ? (arow >> 6) : 0;
    const int amrow = arow & 63;

    f32x4 acc0[4][2] = {};
    f32x4 acc1[DUAL ? 4 : 1][2] = {};
    float f[8][2];
    us8v areg = {};

    auto LOADG = [&](int kg) {
        const TX* Xp = (Xb1 && kg >= 256) ? Xb1 : Xb0;
        const int kr = kg & 255;
#pragma unroll
        for (int j = 0; j < 8; ++j) {
            const TX* p = Xp + (size_t)(kr + brg * 8 + j) * HW + n0 + bc;
            if constexpr (sizeof(TX) == 4) {
                f32x2 v = *(const f32x2*)p;
                f[j][0] = v[0]; f[j][1] = v[1];
            } else {
                us2v v = *(const us2v*)p;
                f[j][0] = bf2f(v[0]); f[j][1] = bf2f(v[1]);
            }
        }
        if (DUAL || tid < 256) {
            const unsigned short* Aw = amat ? Ab1 : Ab0;
            areg = *(const us8v*)(Aw + (size_t)(m0 + amrow) * Ktot + kg + aq8 * 8);
        }
    };

    // B slot: parity-interleaved so staging writes AND fragment reads are consecutive-slot.
    auto STORE = [&](int buf) {
        char* bb = &Bs[buf][0];
#pragma unroll
        for (int j2 = 0; j2 < 2; ++j2) {
            int n = bc + j2;
            u32x4 w;
            w[0] = pk2(f[0][j2], f[1][j2]);
            w[1] = pk2(f[2][j2], f[3][j2]);
            w[2] = pk2(f[4][j2], f[5][j2]);
            w[3] = pk2(f[6][j2], f[7][j2]);
            int slot = brg * 256 + ((n >> 1) | ((n & 1) << 7));
            *(u32x4*)(bb + slot * 16) = w;
        }
        if (DUAL || tid < 256)
            *(us8v*)(&As[buf][0] + (size_t)tid * 16) = areg;
    };

    auto COMPUTE = [&](int buf) {
        const char* bb = &Bs[buf][0];
        const char* ab = &As[buf][0];
        bf16x8 bfr[2];
#pragma unroll
        for (int nj = 0; nj < 2; ++nj) {
            int n = wn + nj * 16 + l15;
            int slot = quad * 256 + ((n >> 1) | ((n & 1) << 7));
            bfr[nj] = *(const bf16x8*)(bb + slot * 16);
        }
        bf16x8 af[4];
#pragma unroll
        for (int mi = 0; mi < 4; ++mi)
            af[mi] = *(const bf16x8*)(ab + (quad * ROWSA + mi * 16 + l15) * 16);
#pragma unroll
        for (int mi = 0; mi < 4; ++mi)
#pragma unroll
            for (int nj = 0; nj < 2; ++nj)
                acc0[mi][nj] = __builtin_amdgcn_mfma_f32_16x16x32_bf16(af[mi], bfr[nj],
                                                                       acc0[mi][nj], 0, 0, 0);
        if constexpr (DUAL) {
#pragma unroll
            for (int mi = 0; mi < 4; ++mi)
                af[mi] = *(const bf16x8*)(ab + (quad * ROWSA + 64 + mi * 16 + l15) * 16);
#pragma unroll
            for (int mi = 0; mi < 4; ++mi)
#pragma unroll
                for (int nj = 0; nj < 2; ++nj)
                    acc1[mi][nj] = __builtin_amdgcn_mfma_f32_16x16x32_bf16(af[mi], bfr[nj],
                                                                           acc1[mi][nj], 0, 0, 0);
        }
    };

    const int nt = Ktot >> 5;
    LOADG(0);
    STORE(0);
    __syncthreads();
    for (int t = 0; t < nt - 1; ++t) {
        LOADG((t + 1) << 5);                 // all global loads for next step, in flight
        __builtin_amdgcn_sched_barrier(0);   // keep them above the MFMAs
        COMPUTE(t & 1);                      // pure LDS+MFMA, no vmcnt waits
        STORE((t + 1) & 1);                  // vmcnt consumed here, after compute
        __syncthreads();
    }
    COMPUTE((nt - 1) & 1);

    // ---- epilogue: C/D layout col(n)=lane&15, row(m)=quad*4+reg ----
#pragma unroll
    for (int mi = 0; mi < 4; ++mi) {
#pragma unroll
        for (int r = 0; r < 4; ++r) {
            int m = m0 + mi * 16 + quad * 4 + r;
            float bv = bias0[m];
#pragma unroll
            for (int nj = 0; nj < 2; ++nj) {
                int n = n0 + wn + nj * 16 + l15;
                size_t off = ((size_t)bz * CDIM + m) * HW + n;
                float v = acc0[mi][nj][r] + bv;
                if (resid) v += resid[off];
                stx(&O0[off], v);
            }
        }
    }
    if constexpr (DUAL) {
#pragma unroll
        for (int mi = 0; mi < 4; ++mi) {
#pragma unroll
            for (int r = 0; r < 4; ++r) {
                int m = m0 + mi * 16 + quad * 4 + r;
                float bv = bias1[m];
#pragma unroll
                for (int nj = 0; nj < 2; ++nj) {
                    int n = n0 + wn + nj * 16 + l15;
                    size_t off = ((size_t)bz * CDIM + m) * HW + n;
                    stx(&O1[off], acc1[mi][nj][r] + bv);
                }
            }
        }
    }
}

// ---------------- MFMA Gram: G[bh][c][d] = sum_n q[c,n]k[d,n], + row sum-of-squares ------
__global__ __launch_bounds__(256) void gram_mfma(
    const unsigned short* __restrict__ q, const unsigned short* __restrict__ k,
    float* __restrict__ Gp, float* __restrict__ sqp, float* __restrict__ skp) {
    const int ch = blockIdx.x;
    const int bh = blockIdx.y;
    const int t = threadIdx.x;
    const int lane = t & 63, w = t >> 6;
    const int row = lane & 31, half = lane >> 5;

    const size_t rb = ((size_t)bh * 32 + row) * HW + ch * 1024 + w * 256 + half * 8;
    const unsigned short* qp = q + rb;
    const unsigned short* kp = k + rb;

    f32x16 acc = {};
    float sq = 0.f, sk = 0.f;
#pragma unroll
    for (int n = 0; n < 256; n += 16) {
        us8v rq = *(const us8v*)(qp + n);
        us8v rk = *(const us8v*)(kp + n);
        bf16x8 aq = __builtin_bit_cast(bf16x8, rq);
        bf16x8 ak = __builtin_bit_cast(bf16x8, rk);
        acc = __builtin_amdgcn_mfma_f32_32x32x16_bf16(aq, ak, acc, 0, 0, 0);
#pragma unroll
        for (int j = 0; j < 8; ++j) {
            float fq = bf2f(rq[j]);
            float fk = bf2f(rk[j]);
            sq += fq * fq;
            sk += fk * fk;
        }
    }
    sq += __shfl_xor(sq, 32, 64);
    sk += __shfl_xor(sk, 32, 64);

    __shared__ float gs[4][1024];
    __shared__ float sqs[4][32];
    __shared__ float sks[4][32];
    if (half == 0) { sqs[w][row] = sq; sks[w][row] = sk; }
    // C/D layout (32x32): col = lane&31, row = (reg&3) + 8*(reg>>2) + 4*(lane>>5)
#pragma unroll
    for (int r = 0; r < 16; ++r) {
        int cr = (r & 3) + 8 * (r >> 2) + 4 * half;
        gs[w][cr * 32 + row] = acc[r];
    }
    __syncthreads();

    float* Gpo = Gp + ((size_t)ch * 64 + bh) * 1024;
#pragma unroll
    for (int j = 0; j < 4; ++j) {
        int idx = j * 256 + t;
        Gpo[idx] = gs[0][idx] + gs[1][idx] + gs[2][idx] + gs[3][idx];
    }
    if (t < 32)
        sqp[((size_t)ch * 64 + bh) * 32 + t] = sqs[0][t] + sqs[1][t] + sqs[2][t] + sqs[3][t];
    else if (t < 64) {
        int c = t - 32;
        skp[((size_t)ch * 64 + bh) * 32 + c] = sks[0][c] + sks[1][c] + sks[2][c] + sks[3][c];
    }
}

// ---------------- sum partials + normalize + temperature + softmax ----------------
__global__ __launch_bounds__(1024) void softmax_kernel(
    const float* __restrict__ Gp, const float* __restrict__ sqp,
    const float* __restrict__ skp, const float* __restrict__ temp,
    float* __restrict__ A) {
    int bh = blockIdx.x;
    int h = bh & 7;
    int c = threadIdx.y, d = threadIdx.x;
    float g = 0.f, qq = 0.f, kk = 0.f;
#pragma unroll
    for (int ch = 0; ch < GCH; ++ch) {
        g += Gp[((size_t)ch * 64 + bh) * 1024 + c * 32 + d];
        qq += sqp[((size_t)ch * 64 + bh) * 32 + c];
        kk += skp[((size_t)ch * 64 + bh) * 32 + d];
    }
    float nq = fmaxf(sqrtf(qq), 1e-12f);
    float nk = fmaxf(sqrtf(kk), 1e-12f);
    float v = g / (nq * nk) * temp[h];
    float m = v;
    for (int s = 16; s > 0; s >>= 1) m = fmaxf(m, __shfl_xor(m, s, 32));
    float e = __expf(v - m);
    float sum = e;
    for (int s = 16; s > 0; s >>= 1) sum += __shfl_xor(sum, s, 32);
    A[(size_t)(bh * 32 + c) * 32 + d] = e / sum;
}

// ---------------- M_b[o, h*32+d] = sum_c W_proj[o, h*32+c] * A[b,h,c,d] -> bf16 ----------------
__global__ __launch_bounds__(256) void build_m(const float* __restrict__ W_proj,
                                               const float* __restrict__ A,
                                               unsigned short* __restrict__ M) {
    int o = blockIdx.x;
    int b = blockIdx.y;
    int t = threadIdx.x;
    int h = t >> 5, d = t & 31;
    const float* Ab = A + (size_t)(b * 8 + h) * 32 * 32;
    float acc = 0.f;
    for (int c = 0; c < 32; ++c)
        acc += W_proj[o * 256 + h * 32 + c] * Ab[c * 32 + d];
    M[((size_t)b * 256 + o) * 256 + t] = f2bf(acc);
}

extern "C" void kernel_launch(void* const* d_in, const int* in_sizes, int n_in,
                              void* d_out, int out_size, void* d_ws, size_t ws_size,
                              hipStream_t stream) {
    const float* x = (const float*)d_in[0];
    const float* y = (const float*)d_in[1];
    const float* z = (const float*)d_in[2];
    const float* W_qr = (const float*)d_in[3];
    const float* b_qr = (const float*)d_in[4];
    const float* W_qd = (const float*)d_in[5];
    const float* b_qd = (const float*)d_in[6];
    const float* W_kf = (const float*)d_in[7];
    const float* b_kf = (const float*)d_in[8];
    const float* W_vf = (const float*)d_in[9];
    const float* b_vf = (const float*)d_in[10];
    const float* W_cat = (const float*)d_in[11];
    const float* b_cat = (const float*)d_in[12];
    const float* W_proj = (const float*)d_in[13];
    const float* b_proj = (const float*)d_in[14];
    const float* temp = (const float*)d_in[15];
    float* out = (float*)d_out;

    char* ws = (char*)d_ws;
    const size_t NT = (size_t)NBATCH * CDIM * HW;  // elements per tensor
    unsigned short* qb = (unsigned short*)ws;
    unsigned short* kb = qb + NT;
    unsigned short* vb = kb + NT;
    char* p = (char*)(vb + NT);
    unsigned short* Wq = (unsigned short*)p;  p += 256 * 512 * 2;
    unsigned short* Wk = (unsigned short*)p;  p += 256 * 256 * 2;
    unsigned short* Wv = (unsigned short*)p;  p += 256 * 256 * 2;
    float* bq  = (float*)p;                   p += 1024;
    float* Gp  = (float*)p;                   p += (size_t)GCH * 64 * 1024 * 4;
    float* sqp = (float*)p;                   p += GCH * 64 * 32 * 4;
    float* skp = (float*)p;                   p += GCH * 64 * 32 * 4;
    float* Aat = (float*)p;                   p += 64 * 32 * 32 * 4;
    unsigned short* Mb = (unsigned short*)p;  p += (size_t)8 * 256 * 256 * 2;

    fuse_wq<<<256, 256, 0, stream>>>(W_cat, W_qr, W_qd, b_qr, b_qd, b_cat, Wq, bq);
    cvt_w<<<256, 256, 0, stream>>>(W_kf, W_vf, Wk, Wv);

    // q = Wq @ [x;y]  (K=512, bf16 out)
    gemm3<false, float, unsigned short><<<1152, 512, 0, stream>>>(
        Wq, nullptr, 0, 512, x, y, bq, nullptr, nullptr, qb, nullptr);
    // fused k,v = Wk@z, Wv@z  (z staged once)
    gemm3<true, float, unsigned short><<<1152, 512, 0, stream>>>(
        Wk, Wv, 0, 256, z, nullptr, b_kf, b_vf, nullptr, kb, vb);

    gram_mfma<<<dim3(GCH, 64), 256, 0, stream>>>(qb, kb, Gp, sqp, skp);
    softmax_kernel<<<64, dim3(32, 32), 0, stream>>>(Gp, sqp, skp, temp, Aat);
    build_m<<<dim3(256, 8), 256, 0, stream>>>(W_proj, Aat, Mb);

    // out = (W_proj@A) @ v + b_proj + z
    gemm3<false, unsigned short, float><<<1152, 512, 0, stream>>>(
        Mb, nullptr, 256 * 256, 256, vb, nullptr, b_proj, nullptr, z, out, nullptr);
}